// Round 10
// baseline (293.757 us; speedup 1.0000x reference)
//
#include <hip/hip_runtime.h>

#define H 1024
#define E 64
#define BT 64           // tokens per block
#define NG 4            // in-block split-K groups
#define KG (H / NG)     // 256 K per group
#define BK 16           // k-chunk per stage
#define NCH (KG / BK)   // 16 chunks
#define R 8             // tokens per thread
#define C 4             // experts per thread

typedef float __attribute__((ext_vector_type(4))) f4;
typedef __attribute__((address_space(1))) const void gvoid;  // global
typedef __attribute__((address_space(3))) void svoid;        // LDS

// Split-K 8x4-tile GEMM, occupancy-first. 512 threads = 4 K-groups x
// (8 tok-grp x 16 exp-grp). Round-8 lesson: 8x8 tiles cap the machine at
// 2048 waves (2/SIMD) and 98KB LDS forced 1 block/CU, so every per-chunk
// vmcnt(0)+barrier idled the CU (VALUBusy 33%). 8x4 tile doubles wave
// count (4096 = 4/SIMD), 64KB LDS gives 2 blocks/CU so one block covers
// the other's barrier drain. Ratio stays fine: per j, 12 ds_read_b128
// (48 LDS-cyc) vs 128 FMA (256 VALU-cyc) -> LDS 75% of VALU -> VALU-bound.
// Swizzle fix (r8 had 4.4M conflicts): phys f4col = logical ^ ((row>>1)&3).
// b-reads hit rows tx+16c (16 distinct tx): even-tx set maps slots
// 0,1,2,3,0,1,2,3 -> 2 rows/slot = 2-way = free (m136). a-reads rows
// ty+8r: 4 distinct ty/wave, 16-lane broadcast, distinct slots. Read-side
// XOR is per-thread constant: xa=ty>>1, xb=(tx>>1)&3 (4r/8c drop mod 4).
__global__ __launch_bounds__(512, 4) void moe_gate_kernel(
    const float* __restrict__ x, const float* __restrict__ W,
    float* __restrict__ out, int T) {
  __shared__ __align__(16) float xs[2][NG][BT][BK];  // 32768 B
  __shared__ __align__(16) float ws[2][NG][E][BK];   // 32768 B (65536 total)
  // epilogue logits tile overlays xs (dead after K loop): 64*65*4 = 16640 B
  float(*ls)[E + 1] = (float(*)[E + 1])xs;

  const int tid = threadIdx.x;
  const int g = tid >> 7;        // K-group 0..3 (wave-uniform: 2 waves/group)
  const int tg = tid & 127;
  const int tx = tg & 15;        // expert group: cols tx + 16c
  const int ty = (tg >> 4) & 7;  // token group: rows ty + 8r
  const int w = tg >> 6;         // wave within group (0/1)
  const int lane = tid & 63;
  const int t0 = blockIdx.x * BT;
  const int kbase = g * KG;

  const int lr = lane >> 2;      // DMA: lane's row within 16-row slab
  const int lc = lane & 3;       // DMA: lane's phys f4 col

  // Stage group g's x-slab (64 rows) and W-slab (64 rows) for chunk ch.
  // Per wave: 2x16 rows each of x and W, 1KB contiguous LDS per issue.
  // Global source pre-swizzled so phys col lc holds logical lc^((row>>1)&3).
  auto stage = [&](int buf, int ch) {
    const int ko = kbase + ch * BK;
#pragma unroll
    for (int m = 0; m < 2; ++m) {
      const int row0 = 32 * w + 16 * m;          // wave-uniform
      const int r = row0 + lr;
      const int cx = lc ^ ((r >> 1) & 3);
      __builtin_amdgcn_global_load_lds(
          (gvoid*)(x + (size_t)(t0 + r) * H + ko + 4 * cx),
          (svoid*)&xs[buf][g][row0][0], 16, 0, 0);
      __builtin_amdgcn_global_load_lds(
          (gvoid*)(W + (size_t)r * H + ko + 4 * cx),
          (svoid*)&ws[buf][g][row0][0], 16, 0, 0);
    }
  };

  float acc[R][C];
#pragma unroll
  for (int r = 0; r < R; ++r)
#pragma unroll
    for (int c = 0; c < C; ++c) acc[r][c] = 0.f;

  stage(0, 0);
  __syncthreads();   // implicit s_waitcnt vmcnt(0) before s_barrier

  const int xa = ty >> 1;         // read-side XOR for a (const per thread)
  const int xb = (tx >> 1) & 3;   // read-side XOR for b
  int buf = 0;
  for (int ch = 0; ch < NCH; ++ch) {
    if (ch + 1 < NCH) stage(buf ^ 1, ch + 1);  // async DMA under compute
#pragma unroll
    for (int j = 0; j < BK / 4; ++j) {
      f4 a[R];
#pragma unroll
      for (int r = 0; r < R; ++r)
        a[r] = *(const f4*)&xs[buf][g][ty + 8 * r][4 * (j ^ xa)];
#pragma unroll
      for (int c = 0; c < C; ++c) {
        const f4 b = *(const f4*)&ws[buf][g][tx + 16 * c][4 * (j ^ xb)];
#pragma unroll
        for (int r = 0; r < R; ++r) {
          acc[r][c] = fmaf(a[r].x, b.x, acc[r][c]);
          acc[r][c] = fmaf(a[r].y, b.y, acc[r][c]);
          acc[r][c] = fmaf(a[r].z, b.z, acc[r][c]);
          acc[r][c] = fmaf(a[r].w, b.w, acc[r][c]);
        }
      }
    }
    __syncthreads();  // drains my DMA (vmcnt 0) + all waves' reads of buf
    buf ^= 1;
  }

  // split-K reduction in LDS: group 0 writes, groups 1..3 add.
  if (g == 0) {
#pragma unroll
    for (int r = 0; r < R; ++r)
#pragma unroll
      for (int c = 0; c < C; ++c)
        ls[ty + 8 * r][tx + 16 * c] = acc[r][c];
  }
  __syncthreads();
  if (g != 0) {
#pragma unroll
    for (int r = 0; r < R; ++r)
#pragma unroll
      for (int c = 0; c < C; ++c)
        atomicAdd(&ls[ty + 8 * r][tx + 16 * c], acc[r][c]);
  }
  __syncthreads();

  // per-token epilogue: 64 lanes, one per token (ls stride 65: 2-way max).
  // top-2 of logits == top-2 of softmax (monotonic); tie-break lower index
  // first (matches jax.lax.top_k).
  if (tid < BT) {
    const int tk = tid;
    float m1 = -1e30f, m2 = -1e30f;
    int i1 = 0, i2 = 0;
#pragma unroll
    for (int e = 0; e < E; ++e) {
      float v = ls[tk][e];
      if (v > m1) {
        m2 = m1; i2 = i1;
        m1 = v;  i1 = e;
      } else if (v > m2) {
        m2 = v; i2 = e;
      }
    }
    float s = 0.f;
#pragma unroll
    for (int e = 0; e < E; ++e) s += expf(ls[tk][e] - m1);
    float p1 = 1.f / s;                 // exp(m1-m1)/s
    float p2 = expf(m2 - m1) / s;
    // second softmax over [p1, p2] (p1 >= p2 so exponent <= 0: stable)
    float e12 = expf(p2 - p1);
    float s1 = 1.f / (1.f + e12);
    float s2 = e12 * s1;

    size_t t = (size_t)(t0 + tk);
    out[t * 2 + 0] = s1;
    out[t * 2 + 1] = s2;
    float* idxo = out + (size_t)2 * T;
    idxo[t * 2 + 0] = (float)i1;
    idxo[t * 2 + 1] = (float)i2;
  }

  // trailing scalar output: zeros(())
  if (blockIdx.x == 0 && tid == 0) out[(size_t)4 * T] = 0.f;
}

extern "C" void kernel_launch(void* const* d_in, const int* in_sizes, int n_in,
                              void* d_out, int out_size, void* d_ws, size_t ws_size,
                              hipStream_t stream) {
  const float* x = (const float*)d_in[0];
  const float* W = (const float*)d_in[1];
  float* out = (float*)d_out;
  const int T = in_sizes[0] / H;  // 4*8192 = 32768 tokens
  dim3 grid(T / BT), block(512);
  hipLaunchKernelGGL(moe_gate_kernel, grid, block, 0, stream, x, W, out, T);
}

// Round 11
// 250.157 us; speedup vs baseline: 1.1743x; 1.1743x over previous
//
#include <hip/hip_runtime.h>

#define H 1024
#define E 64
#define BT 64           // tokens per block
#define NG 4            // in-block split-K groups (1 wave each)
#define KG (H / NG)     // 256 K per group
#define BK 16           // k-chunk per stage
#define NCH (KG / BK)   // 16 chunks
#define R 8             // tokens per thread
#define C 8             // experts per thread
#define PS 72           // partial-tile row stride (floats): bank=(8ty+tx)%32 -> 2-way

typedef float __attribute__((ext_vector_type(4))) f4;
typedef __attribute__((address_space(1))) const void gvoid;  // global
typedef __attribute__((address_space(3))) void svoid;        // LDS

// Split-K 8x8 (ratio 16 FMA/ds_read_b128 -> LDS-pipe ~41us, the new wall).
// Fixes for r8/r10 failures:
//  - 64KB LDS -> 2 blocks/CU co-resident (r8 had 1: barriers idled the CU)
//  - amdgpu_waves_per_eu(2,2): stops the allocator's "2x min occupancy"
//    habit ((512,4)->64 regs, 21MB spill in r10). Need ~125 regs.
//  - NO atomics: r8/r10's 4.3M "bank conflicts" were the split-K atomicAdd
//    reduction. Groups 1-3 write stride-72 partial tiles (2-way banks),
//    group 0 sums in registers; top-2+softmax fully in-register via
//    __shfl_xor -- the LDS logits tile is gone.
// Main-loop banks: rows ty+8r (a) / tx+8c (b), phys f4col = logical ^
// ((row>>1)&3), pre-swizzled at the DMA *source* (dest stays linear, m173).
// Per (r,j): 8 distinct addrs -> even rows banks 0-15 slots distinct, odd
// rows banks 16-31 -> conflict-free. DMA: 64 lanes x 16B = 1KB linear.
__global__ __launch_bounds__(256) __attribute__((amdgpu_waves_per_eu(2, 2)))
void moe_gate_kernel(const float* __restrict__ x, const float* __restrict__ W,
                     float* __restrict__ out, int T) {
  __shared__ __align__(16) float smem[16384];       // 64 KB
  auto xs = (float(*)[NG][BT][BK])smem;             // [2][4][64][16]
  auto ws = (float(*)[NG][E][BK])(smem + 8192);     // [2][4][64][16]
  auto part = (float(*)[BT][PS])smem;               // [3][64][72], post-loop overlay

  const int tid = threadIdx.x;
  const int g = tid >> 6;          // K-group == wave id
  const int lane = tid & 63;
  const int tx = lane & 7;         // expert cols tx + 8c
  const int ty = lane >> 3;        // token rows ty + 8r
  const int t0 = blockIdx.x * BT;
  const int kbase = g * KG;
  const int lr = lane >> 2;        // DMA row within 16-row slab
  const int lc = lane & 3;         // DMA phys f4 col

  // per-lane DMA source pointers (chunk 0), source pre-swizzled
  const float* xsrc[4];
  const float* wsrc[4];
#pragma unroll
  for (int m = 0; m < 4; ++m) {
    const int r = 16 * m + lr;
    const int cx = lc ^ ((r >> 1) & 3);
    xsrc[m] = x + (size_t)(t0 + r) * H + kbase + 4 * cx;
    wsrc[m] = W + (size_t)r * H + kbase + 4 * cx;
  }

  float acc[R][C];
#pragma unroll
  for (int r = 0; r < R; ++r)
#pragma unroll
    for (int c = 0; c < C; ++c) acc[r][c] = 0.f;

  // prologue: stage chunk 0
#pragma unroll
  for (int m = 0; m < 4; ++m) {
    __builtin_amdgcn_global_load_lds((gvoid*)xsrc[m],
                                     (svoid*)&xs[0][g][16 * m][0], 16, 0, 0);
    __builtin_amdgcn_global_load_lds((gvoid*)wsrc[m],
                                     (svoid*)&ws[0][g][16 * m][0], 16, 0, 0);
  }
  __syncthreads();

  const int xa = ty >> 1;          // read-side XOR (per-thread const)
  const int xb = tx >> 1;
  int buf = 0;
  for (int ch = 0; ch < NCH; ++ch) {
    if (ch + 1 < NCH) {            // async DMA for next chunk under compute
      const int ko = (ch + 1) * BK;
#pragma unroll
      for (int m = 0; m < 4; ++m) {
        __builtin_amdgcn_global_load_lds((gvoid*)(xsrc[m] + ko),
            (svoid*)&xs[buf ^ 1][g][16 * m][0], 16, 0, 0);
        __builtin_amdgcn_global_load_lds((gvoid*)(wsrc[m] + ko),
            (svoid*)&ws[buf ^ 1][g][16 * m][0], 16, 0, 0);
      }
    }
#pragma unroll
    for (int j = 0; j < BK / 4; ++j) {
      f4 a[R];
#pragma unroll
      for (int r = 0; r < R; ++r)
        a[r] = *(const f4*)&xs[buf][g][ty + 8 * r][4 * (j ^ xa)];
#pragma unroll
      for (int c = 0; c < C; ++c) {
        const f4 b = *(const f4*)&ws[buf][g][tx + 8 * c][4 * (j ^ xb)];
#pragma unroll
        for (int r = 0; r < R; ++r) {
          acc[r][c] = fmaf(a[r].x, b.x, acc[r][c]);
          acc[r][c] = fmaf(a[r].y, b.y, acc[r][c]);
          acc[r][c] = fmaf(a[r].z, b.z, acc[r][c]);
          acc[r][c] = fmaf(a[r].w, b.w, acc[r][c]);
        }
      }
    }
    __syncthreads();  // drains DMA (vmcnt0) + all waves' reads of buf
    buf ^= 1;
  }

  // split-K reduction, no atomics: groups 1-3 write stride-72 partials.
  if (g != 0) {
#pragma unroll
    for (int r = 0; r < R; ++r)
#pragma unroll
      for (int c = 0; c < C; ++c)
        part[g - 1][ty + 8 * r][tx + 8 * c] = acc[r][c];
  }
  __syncthreads();

  if (g == 0) {
#pragma unroll
    for (int p = 0; p < NG - 1; ++p)
#pragma unroll
      for (int r = 0; r < R; ++r)
#pragma unroll
        for (int c = 0; c < C; ++c)
          acc[r][c] += part[p][ty + 8 * r][tx + 8 * c];

    // in-register epilogue: row (ty+8r) lives in lanes 8ty..8ty+7.
    // top-2 with tie-break lower-index (matches jax.lax.top_k), then
    // softmax denom via shfl tree; monotonic => top-2 of logits ok.
    float* idxo = out + (size_t)2 * T;
#pragma unroll
    for (int r = 0; r < R; ++r) {
      float m1 = acc[r][0];
      int i1 = tx;
      float m2 = -1e30f;
      int i2 = 0;
#pragma unroll
      for (int c = 1; c < C; ++c) {
        float v = acc[r][c];
        int idx = tx + 8 * c;
        if (v > m1) {
          m2 = m1; i2 = i1;
          m1 = v;  i1 = idx;
        } else if (v > m2) {
          m2 = v; i2 = idx;
        }
      }
#pragma unroll
      for (int d = 1; d <= 4; d <<= 1) {
        float om1 = __shfl_xor(m1, d); int oi1 = __shfl_xor(i1, d);
        float om2 = __shfl_xor(m2, d); int oi2 = __shfl_xor(i2, d);
        bool w1 = (om1 > m1) || (om1 == m1 && oi1 < i1);
        float n1 = w1 ? om1 : m1; int n1i = w1 ? oi1 : i1;
        float ca = w1 ? m1 : om1; int cai = w1 ? i1 : oi1;
        float cb = w1 ? om2 : m2; int cbi = w1 ? oi2 : i2;
        bool w2 = (ca > cb) || (ca == cb && cai < cbi);
        m1 = n1; i1 = n1i;
        m2 = w2 ? ca : cb; i2 = w2 ? cai : cbi;
      }
      float se = 0.f;
#pragma unroll
      for (int c = 0; c < C; ++c) se += expf(acc[r][c] - m1);
#pragma unroll
      for (int d = 1; d <= 4; d <<= 1) se += __shfl_xor(se, d);
      if (tx == 0) {
        float p1 = 1.f / se;                 // exp(m1-m1)/se
        float p2 = expf(m2 - m1) / se;
        float e12 = expf(p2 - p1);           // p1 >= p2: stable
        float s1 = 1.f / (1.f + e12);
        float s2 = e12 * s1;
        size_t t = (size_t)(t0 + ty + 8 * r);
        out[t * 2 + 0] = s1;
        out[t * 2 + 1] = s2;
        idxo[t * 2 + 0] = (float)i1;
        idxo[t * 2 + 1] = (float)i2;
      }
    }
  }

  // trailing scalar output: zeros(())
  if (blockIdx.x == 0 && tid == 0) out[(size_t)4 * T] = 0.f;
}

extern "C" void kernel_launch(void* const* d_in, const int* in_sizes, int n_in,
                              void* d_out, int out_size, void* d_ws, size_t ws_size,
                              hipStream_t stream) {
  const float* x = (const float*)d_in[0];
  const float* W = (const float*)d_in[1];
  float* out = (float*)d_out;
  const int T = in_sizes[0] / H;  // 4*8192 = 32768 tokens
  dim3 grid(T / BT), block(256);
  hipLaunchKernelGGL(moe_gate_kernel, grid, block, 0, stream, x, W, out, T);
}

// Round 12
// 240.282 us; speedup vs baseline: 1.2226x; 1.0411x over previous
//
#include <hip/hip_runtime.h>

#define H 1024
#define E 64
#define BT 64           // tokens per block
#define NG 4            // in-block split-K groups (1 wave each)
#define KG (H / NG)     // 256 K per group
#define BK 16           // k-chunk per stage
#define NCH (KG / BK)   // 16 chunks
#define R 8             // tokens per thread
#define C 8             // experts per thread
#define PS 72           // partial-tile row stride (floats): bank=(8ty+tx)%32 -> 2-way

typedef float __attribute__((ext_vector_type(4))) f4;
typedef __attribute__((address_space(1))) const void gvoid;  // global
typedef __attribute__((address_space(3))) void svoid;        // LDS

// Split-K 8x8 (ratio 16 FMA/ds_read_b128 -> LDS-pipe ~41us wall).
// r11 counters: conflicts 0 (atomic-free reduction works), but VGPR=128
// with 5.6MB scratch writes -> in-loop spill stalls = the 75us gap
// (17.4K cyc/chunk vs 6K model). Allocator habit (measured r7/r10/r11):
// targets 2x the declared min occupancy. Fix: __launch_bounds__(256,1)
// -> cap 512, target 2/EU = 256 regs -> ~150-reg kernel fits, NO spill.
// Occupancy unchanged: LDS 64KB pins 2 blocks/CU = 8 waves (2/SIMD);
// 2 waves x 160 regs = 320 << 2048/SIMD pool.
// Main-loop banks: rows ty+8r (a) / tx+8c (b), phys f4col = logical ^
// ((row>>1)&3), pre-swizzled at the DMA *source* (dest linear, m173).
// 8 distinct addrs -> 8 disjoint 4-bank groups -> conflict-free (r11: 0).
__global__ __launch_bounds__(256, 1)
void moe_gate_kernel(const float* __restrict__ x, const float* __restrict__ W,
                     float* __restrict__ out, int T) {
  __shared__ __align__(16) float smem[16384];       // 64 KB
  auto xs = (float(*)[NG][BT][BK])smem;             // [2][4][64][16]
  auto ws = (float(*)[NG][E][BK])(smem + 8192);     // [2][4][64][16]
  auto part = (float(*)[BT][PS])smem;               // [3][64][72], post-loop overlay

  const int tid = threadIdx.x;
  const int g = tid >> 6;          // K-group == wave id
  const int lane = tid & 63;
  const int tx = lane & 7;         // expert cols tx + 8c
  const int ty = lane >> 3;        // token rows ty + 8r
  const int t0 = blockIdx.x * BT;
  const int kbase = g * KG;
  const int lr = lane >> 2;        // DMA row within 16-row slab
  const int lc = lane & 3;         // DMA phys f4 col

  // per-lane DMA source pointers (chunk 0), source pre-swizzled
  const float* xsrc[4];
  const float* wsrc[4];
#pragma unroll
  for (int m = 0; m < 4; ++m) {
    const int r = 16 * m + lr;
    const int cx = lc ^ ((r >> 1) & 3);
    xsrc[m] = x + (size_t)(t0 + r) * H + kbase + 4 * cx;
    wsrc[m] = W + (size_t)r * H + kbase + 4 * cx;
  }

  float acc[R][C];
#pragma unroll
  for (int r = 0; r < R; ++r)
#pragma unroll
    for (int c = 0; c < C; ++c) acc[r][c] = 0.f;

  // prologue: stage chunk 0
#pragma unroll
  for (int m = 0; m < 4; ++m) {
    __builtin_amdgcn_global_load_lds((gvoid*)xsrc[m],
                                     (svoid*)&xs[0][g][16 * m][0], 16, 0, 0);
    __builtin_amdgcn_global_load_lds((gvoid*)wsrc[m],
                                     (svoid*)&ws[0][g][16 * m][0], 16, 0, 0);
  }
  __syncthreads();

  const int xa = ty >> 1;          // read-side XOR (per-thread const)
  const int xb = tx >> 1;
  int buf = 0;
  for (int ch = 0; ch < NCH; ++ch) {
    if (ch + 1 < NCH) {            // async DMA for next chunk under compute
      const int ko = (ch + 1) * BK;
#pragma unroll
      for (int m = 0; m < 4; ++m) {
        __builtin_amdgcn_global_load_lds((gvoid*)(xsrc[m] + ko),
            (svoid*)&xs[buf ^ 1][g][16 * m][0], 16, 0, 0);
        __builtin_amdgcn_global_load_lds((gvoid*)(wsrc[m] + ko),
            (svoid*)&ws[buf ^ 1][g][16 * m][0], 16, 0, 0);
      }
    }
#pragma unroll
    for (int j = 0; j < BK / 4; ++j) {
      f4 a[R];
#pragma unroll
      for (int r = 0; r < R; ++r)
        a[r] = *(const f4*)&xs[buf][g][ty + 8 * r][4 * (j ^ xa)];
#pragma unroll
      for (int c = 0; c < C; ++c) {
        const f4 b = *(const f4*)&ws[buf][g][tx + 8 * c][4 * (j ^ xb)];
#pragma unroll
        for (int r = 0; r < R; ++r) {
          acc[r][c] = fmaf(a[r].x, b.x, acc[r][c]);
          acc[r][c] = fmaf(a[r].y, b.y, acc[r][c]);
          acc[r][c] = fmaf(a[r].z, b.z, acc[r][c]);
          acc[r][c] = fmaf(a[r].w, b.w, acc[r][c]);
        }
      }
    }
    __syncthreads();  // drains DMA (vmcnt0) + all waves' reads of buf
    buf ^= 1;
  }

  // split-K reduction, no atomics: groups 1-3 write stride-72 partials.
  if (g != 0) {
#pragma unroll
    for (int r = 0; r < R; ++r)
#pragma unroll
      for (int c = 0; c < C; ++c)
        part[g - 1][ty + 8 * r][tx + 8 * c] = acc[r][c];
  }
  __syncthreads();

  if (g == 0) {
#pragma unroll
    for (int p = 0; p < NG - 1; ++p)
#pragma unroll
      for (int r = 0; r < R; ++r)
#pragma unroll
        for (int c = 0; c < C; ++c)
          acc[r][c] += part[p][ty + 8 * r][tx + 8 * c];

    // in-register epilogue: row (ty+8r) lives in lanes 8ty..8ty+7.
    // top-2 with tie-break lower-index (matches jax.lax.top_k), then
    // softmax denom via shfl tree; monotonic => top-2 of logits ok.
    float* idxo = out + (size_t)2 * T;
#pragma unroll
    for (int r = 0; r < R; ++r) {
      float m1 = acc[r][0];
      int i1 = tx;
      float m2 = -1e30f;
      int i2 = 0;
#pragma unroll
      for (int c = 1; c < C; ++c) {
        float v = acc[r][c];
        int idx = tx + 8 * c;
        if (v > m1) {
          m2 = m1; i2 = i1;
          m1 = v;  i1 = idx;
        } else if (v > m2) {
          m2 = v; i2 = idx;
        }
      }
#pragma unroll
      for (int d = 1; d <= 4; d <<= 1) {
        float om1 = __shfl_xor(m1, d); int oi1 = __shfl_xor(i1, d);
        float om2 = __shfl_xor(m2, d); int oi2 = __shfl_xor(i2, d);
        bool w1 = (om1 > m1) || (om1 == m1 && oi1 < i1);
        float n1 = w1 ? om1 : m1; int n1i = w1 ? oi1 : i1;
        float ca = w1 ? m1 : om1; int cai = w1 ? i1 : oi1;
        float cb = w1 ? om2 : m2; int cbi = w1 ? oi2 : i2;
        bool w2 = (ca > cb) || (ca == cb && cai < cbi);
        m1 = n1; i1 = n1i;
        m2 = w2 ? ca : cb; i2 = w2 ? cai : cbi;
      }
      float se = 0.f;
#pragma unroll
      for (int c = 0; c < C; ++c) se += expf(acc[r][c] - m1);
#pragma unroll
      for (int d = 1; d <= 4; d <<= 1) se += __shfl_xor(se, d);
      if (tx == 0) {
        float p1 = 1.f / se;                 // exp(m1-m1)/se
        float p2 = expf(m2 - m1) / se;
        float e12 = expf(p2 - p1);           // p1 >= p2: stable
        float s1 = 1.f / (1.f + e12);
        float s2 = e12 * s1;
        size_t t = (size_t)(t0 + ty + 8 * r);
        out[t * 2 + 0] = s1;
        out[t * 2 + 1] = s2;
        idxo[t * 2 + 0] = (float)i1;
        idxo[t * 2 + 1] = (float)i2;
      }
    }
  }

  // trailing scalar output: zeros(())
  if (blockIdx.x == 0 && tid == 0) out[(size_t)4 * T] = 0.f;
}

extern "C" void kernel_launch(void* const* d_in, const int* in_sizes, int n_in,
                              void* d_out, int out_size, void* d_ws, size_t ws_size,
                              hipStream_t stream) {
  const float* x = (const float*)d_in[0];
  const float* W = (const float*)d_in[1];
  float* out = (float*)d_out;
  const int T = in_sizes[0] / H;  // 4*8192 = 32768 tokens
  dim3 grid(T / BT), block(256);
  hipLaunchKernelGGL(moe_gate_kernel, grid, block, 0, stream, x, W, out, T);
}